// Round 22
// baseline (95.470 us; speedup 1.0000x reference)
//
#include <hip/hip_runtime.h>
#include <hip/hip_bf16.h>
#include <math.h>

#define B_ 4
#define H_ 64
#define W_ 64
#define C_ 64
#define F_ 64
#define N_ 4096

typedef __attribute__((ext_vector_type(8))) short bf16x8;
typedef __attribute__((ext_vector_type(4))) short bf16x4;
typedef __attribute__((ext_vector_type(4))) float f32x4;
typedef __attribute__((ext_vector_type(2))) int i32x2;

#define GLOAD_LDS(g, l) \
  __builtin_amdgcn_global_load_lds( \
      (__attribute__((address_space(1))) const void*)(g), \
      (__attribute__((address_space(3))) void*)(l), 16, 0, 0)

static __device__ __forceinline__ short f2bf(float f){
  union { __hip_bfloat16 h; short s; } u;
  u.h = __float2bfloat16(f);
  return u.s;
}

// ---------------- merged prep: x fp32->bf16 (blocks 0..1023) + weights->Wt (blocks 1024..1599) ----
__global__ __launch_bounds__(256) void prep_kernel(
    const float* __restrict__ x,
    const float* __restrict__ Wk, const float* __restrict__ Wq,
    const float* __restrict__ Wv, const float* __restrict__ Wr,
    short* __restrict__ xb, short* __restrict__ Wt)
{
  const int bid = blockIdx.x;
  if (bid < 1024){
    const int i4 = bid * 256 + threadIdx.x;          // over B*N*C/4
    const float4 v = ((const float4*)x)[i4];
    bf16x4 o;
    o[0] = f2bf(v.x); o[1] = f2bf(v.y); o[2] = f2bf(v.z); o[3] = f2bf(v.w);
    ((bf16x4*)xb)[i4] = o;
  } else {
    const int gid = (bid - 1024) * 256 + threadIdx.x;  // 256*576
    const int oc = gid / 576;
    const int kk = gid % 576;                          // (ky*3+kx)*64 + ci
    const int srcofs = (kk >> 6) * 4096 + (kk & 63) * 64 + (oc & 63);
    const float* src = (oc < 64) ? Wk : (oc < 128) ? Wq : (oc < 192) ? Wv : Wr;
    Wt[gid] = f2bf(src[srcofs]);
  }
}

// ---------------- conv QKV as implicit-GEMM MFMA: 32 px/block (control) ----------------
__global__ __launch_bounds__(256) void conv_qkv_mfma(
    const short* __restrict__ xb, const short* __restrict__ Wt,
    const float* __restrict__ bk, const float* __restrict__ bq,
    const float* __restrict__ bv,
    short* __restrict__ qo, short* __restrict__ ko, short* __restrict__ vt)
{
  const int lane = threadIdx.x & 63;
  const int w    = threadIdx.x >> 6;
  const int lrow = lane & 15;
  const int lkb  = lane >> 4;
  const int p0   = blockIdx.x << 5;
  const int b    = p0 >> 12;
  const int y    = (p0 >> 6) & 63;
  const int x0   = p0 & 63;

  f32x4 ak[2], aq[2], av[2];
  #pragma unroll
  for (int m = 0; m < 2; ++m)
    #pragma unroll
    for (int i = 0; i < 4; ++i){ ak[m][i] = 0.f; aq[m][i] = 0.f; av[m][i] = 0.f; }

  const short* wr_k = Wt + (      w * 16 + lrow) * 576;
  const short* wr_q = Wt + ( 64 + w * 16 + lrow) * 576;
  const short* wr_v = Wt + (128 + w * 16 + lrow) * 576;

  #pragma unroll
  for (int ks = 0; ks < 18; ++ks){
    const int kxy = ks >> 1;
    const int ky  = kxy / 3;
    const int kx  = kxy - ky * 3;
    const int ci0 = (ks & 1) << 5;
    const int yy  = y + ky - 1;
    const bf16x8 wk8 = *(const bf16x8*)(wr_k + ks * 32 + lkb * 8);
    const bf16x8 wq8 = *(const bf16x8*)(wr_q + ks * 32 + lkb * 8);
    const bf16x8 wv8 = *(const bf16x8*)(wr_v + ks * 32 + lkb * 8);
    #pragma unroll
    for (int m = 0; m < 2; ++m){
      const int xx = x0 + m * 16 + lrow + kx - 1;
      bf16x8 a = {0,0,0,0,0,0,0,0};
      if ((unsigned)yy < 64u && (unsigned)xx < 64u)
        a = *(const bf16x8*)(xb + ((((b << 6) + yy) << 6) + xx) * 64 + ci0 + lkb * 8);
      ak[m] = __builtin_amdgcn_mfma_f32_16x16x32_bf16(a, wk8, ak[m], 0, 0, 0);
      aq[m] = __builtin_amdgcn_mfma_f32_16x16x32_bf16(a, wq8, aq[m], 0, 0, 0);
      av[m] = __builtin_amdgcn_mfma_f32_16x16x32_bf16(a, wv8, av[m], 0, 0, 0);
    }
  }
  const int oc = w * 16 + lrow;
  const float bkv = bk[oc], bqv = bq[oc], bvv = bv[oc];
  #pragma unroll
  for (int m = 0; m < 2; ++m){
    bf16x4 vp;
    #pragma unroll
    for (int i = 0; i < 4; ++i){
      const int p = p0 + m * 16 + (lkb << 2) + i;
      const float kvv = ak[m][i] + bkv;
      ko[p * 64 + oc] = f2bf(kvv > 0.f ? kvv : expm1f(kvv));            // elu
      const float qvv = aq[m][i] + bqv;
      const float qe  = (qvv > 0.f ? qvv : expm1f(qvv)) * 0.125f;       // elu * 1/sqrt(F)
      qo[p * 64 + oc] = f2bf(qe);
      const float vvv = av[m][i] + bvv;
      vp[i] = f2bf(vvv > 0.f ? vvv : 0.f);                              // relu
    }
    *(bf16x4*)(vt + ((size_t)(b * 64 + oc)) * 4096 + (p0 & 4095) + m * 16 + (lkb << 2)) = vp;
  }
}

// ---------------- flash attention: 8 waves/block, swapped QK^T, K+V DMA-staged,
//                  V-frags HOISTED (loaded once per tile, shared by both row groups) ----------------
__global__ __launch_bounds__(512, 4) void attn_kernel(
    const short* __restrict__ q, const short* __restrict__ k,
    const short* __restrict__ vt, float* __restrict__ Op,
    float* __restrict__ lp, int split)
{
  const int tid  = threadIdx.x;
  const int lane = tid & 63;
  const int wv   = tid >> 6;               // 0..7
  const int lrow = lane & 15;
  const int lkb  = lane >> 4;

  const int bid  = blockIdx.x;
  const int b    = bid / (16 * split);
  const int rem  = bid % (16 * split);
  const int rt   = rem / split;            // 256-row tile (0..15)
  const int sp   = rem % split;
  const int rbase = (rt << 8) + (wv << 5); // this wave's 32 rows
  const int tiles = (N_ / 64) / split;
  const int ct0   = sp * tiles;

  const short* qb = q  + (size_t)b * N_ * F_;
  const short* kb = k  + (size_t)b * N_ * F_;
  const short* vb = vt + (size_t)b * F_ * N_;

  // Q fragments (B-operand of the swapped QK^T)
  const bf16x8 aq00 = *(const bf16x8*)(qb + (rbase +      lrow) * F_ + lkb * 8);
  const bf16x8 aq01 = *(const bf16x8*)(qb + (rbase +      lrow) * F_ + 32 + lkb * 8);
  const bf16x8 aq10 = *(const bf16x8*)(qb + (rbase + 16 + lrow) * F_ + lkb * 8);
  const bf16x8 aq11 = *(const bf16x8*)(qb + (rbase + 16 + lrow) * F_ + 32 + lkb * 8);

  __shared__ short kbuf[2][64 * 64];       // 16 KB
  __shared__ short vbuf[2][64 * 64];       // 16 KB
  __shared__ short pbuf[8][16][64];        // 16 KB: per-wave, shared across row groups

  // staging via global_load_lds: LDS dest LINEAR (tid*16); XOR swizzle applied to the
  // GLOBAL source chunk (m201 both-sides rule); read side unchanged.
  const int srow  = tid >> 3;              // 0..63
  const int sc16s = (tid & 7) ^ (srow & 7);  // pre-swizzled source chunk

  f32x4 oacc[2][4];
  float l_r[2] = {0.f, 0.f};
  #pragma unroll
  for (int g = 0; g < 2; ++g)
    #pragma unroll
    for (int fs = 0; fs < 4; ++fs)
      #pragma unroll
      for (int i = 0; i < 4; ++i) oacc[g][fs][i] = 0.f;

  // ---- stage tile 0 (DMA) ----
  int cbase = ct0 << 6;
  GLOAD_LDS(kb + (cbase + srow) * 64 + sc16s * 8, (char*)kbuf[0] + tid * 16);
  GLOAD_LDS(vb + (size_t)srow * N_ + cbase + sc16s * 8, (char*)vbuf[0] + tid * 16);
  __syncthreads();

  int cur = 0;
  for (int t = 0; t < tiles; ++t){
    cbase = (ct0 + t) << 6;
    // issue next-tile DMA into the just-freed buffer (drained at this tile's end barrier)
    if (t + 1 < tiles){
      const int cb2 = (ct0 + t + 1) << 6;
      const int nxt = cur ^ 1;
      GLOAD_LDS(kb + (cb2 + srow) * 64 + sc16s * 8, (char*)kbuf[nxt] + tid * 16);
      GLOAD_LDS(vb + (size_t)srow * N_ + cb2 + sc16s * 8, (char*)vbuf[nxt] + tid * 16);
    }
    const char* kc = (const char*)kbuf[cur];
    const char* vc = (const char*)vbuf[cur];
    // ---- S^T = K Q^T (A = K-frag from LDS, B = Q regs) ----
    f32x4 s0[4], s1[4];
    #pragma unroll
    for (int n = 0; n < 4; ++n){
      #pragma unroll
      for (int i = 0; i < 4; ++i){ s0[n][i] = 0.f; s1[n][i] = 0.f; }
    }
    __builtin_amdgcn_s_setprio(1);
    #pragma unroll
    for (int n = 0; n < 4; ++n){
      const int r   = n * 16 + lrow;
      const int swz = (r & 7) << 4;
      const bf16x8 b0 = *(const bf16x8*)(kc + r * 128 + ((lkb * 16) ^ swz));
      const bf16x8 b1 = *(const bf16x8*)(kc + r * 128 + ((64 + lkb * 16) ^ swz));
      s0[n] = __builtin_amdgcn_mfma_f32_16x16x32_bf16(b0, aq00, s0[n], 0, 0, 0);
      s0[n] = __builtin_amdgcn_mfma_f32_16x16x32_bf16(b1, aq01, s0[n], 0, 0, 0);
      s1[n] = __builtin_amdgcn_mfma_f32_16x16x32_bf16(b0, aq10, s1[n], 0, 0, 0);
      s1[n] = __builtin_amdgcn_mfma_f32_16x16x32_bf16(b1, aq11, s1[n], 0, 0, 0);
    }
    __builtin_amdgcn_s_setprio(0);
    // ---- V fragments: loaded ONCE per tile, shared by both row groups (r14 structure) ----
    bf16x8 bvf[2][4];
    #pragma unroll
    for (int kc2 = 0; kc2 < 2; ++kc2)
      #pragma unroll
      for (int fs = 0; fs < 4; ++fs){
        const int r   = fs * 16 + lrow;
        const int swz = (r & 7) << 4;
        bvf[kc2][fs] = *(const bf16x8*)(vc + r * 128 + ((kc2 * 64 + lkb * 16) ^ swz));
      }
    const int rswz = (lrow & 7) << 4;
    char* pgc = (char*)&pbuf[wv][0][0];
    #pragma unroll
    for (int g = 0; g < 2; ++g){
      f32x4* s = g ? s1 : s0;
      // ---- diagonal: only when this wave's 16 q-rows fall inside this tile ----
      const int dq = rbase + g * 16 - cbase;     // wave-uniform
      if (dq >= 0 && dq < 64){
        #pragma unroll
        for (int n = 0; n < 4; ++n)
          if (dq == n * 16){
            const int di = lrow - (lkb << 2);
            #pragma unroll
            for (int i = 0; i < 4; ++i)
              if (di == i) s[n][i] = 0.f;
          }
      }
      // ---- p = exp(s-16); lane-local l; vector P store (k lane-contiguous) ----
      #pragma unroll
      for (int n = 0; n < 4; ++n){
        union { float f; unsigned u; } c0, c1, c2, c3;
        c0.f = __expf(s[n][0] - 16.f);
        c1.f = __expf(s[n][1] - 16.f);
        c2.f = __expf(s[n][2] - 16.f);
        c3.f = __expf(s[n][3] - 16.f);
        l_r[g] += (c0.f + c1.f) + (c2.f + c3.f);
        i32x2 pk;
        pk[0] = (int)((c1.u & 0xFFFF0000u) | (c0.u >> 16));   // bf16 trunc pack
        pk[1] = (int)((c3.u & 0xFFFF0000u) | (c2.u >> 16));
        *(i32x2*)(pgc + lrow * 128 + ((n * 32 + lkb * 8) ^ rswz)) = pk;
      }
      // ---- A-frag P reads + PV (V from hoisted registers) ----
      const bf16x8 pa0 = *(const bf16x8*)(pgc + lrow * 128 + ((lkb * 16) ^ rswz));
      const bf16x8 pa1 = *(const bf16x8*)(pgc + lrow * 128 + ((64 + lkb * 16) ^ rswz));
      __builtin_amdgcn_s_setprio(1);
      #pragma unroll
      for (int kc2 = 0; kc2 < 2; ++kc2){
        const bf16x8 pa = kc2 ? pa1 : pa0;
        #pragma unroll
        for (int fs = 0; fs < 4; ++fs)
          oacc[g][fs] = __builtin_amdgcn_mfma_f32_16x16x32_bf16(pa, bvf[kc2][fs], oacc[g][fs], 0, 0, 0);
      }
      __builtin_amdgcn_s_setprio(0);
    }
    // ---- single barrier per tile (drains the next-tile DMA + converges readers) ----
    __syncthreads();
    cur ^= 1;
  }
  // ---- l: single cross-lane reduce (lanes lrow,+16,+32,+48 share q-row) ----
  #pragma unroll
  for (int g = 0; g < 2; ++g){
    l_r[g] += __shfl_xor(l_r[g], 16, 64);
    l_r[g] += __shfl_xor(l_r[g], 32, 64);
  }
  // ---- store fp32 unnormalized partials (coalesced) + l ----
  float* Ob = Op + (size_t)(b * split + sp) * N_ * F_;
  #pragma unroll
  for (int g = 0; g < 2; ++g){
    #pragma unroll
    for (int i = 0; i < 4; ++i){
      const int row = rbase + g * 16 + lkb * 4 + i;
      #pragma unroll
      for (int fs = 0; fs < 4; ++fs)
        Ob[(size_t)row * F_ + fs * 16 + lrow] = oacc[g][fs][i];
    }
    if (lane < 16)
      lp[(size_t)(b * split + sp) * N_ + rbase + g * 16 + lane] = l_r[g];
  }
}

// ---------------- combine fp32 partials, float4-vectorized -> bf16 ----------------
__global__ __launch_bounds__(256) void combine_kernel(
    const float* __restrict__ Op, const float* __restrict__ lp,
    short* __restrict__ ob, int split)
{
  const int gid4 = blockIdx.x * 256 + threadIdx.x;   // over B*N*F/4
  const int f4 = gid4 & 15;
  const int n  = (gid4 >> 4) & (N_ - 1);
  const int b  = gid4 >> 16;
  float L = 0.f;
  float4 O = {0.f, 0.f, 0.f, 0.f};
  for (int s = 0; s < split; ++s){
    L += lp[(size_t)(b * split + s) * N_ + n];
    const float4 v = *(const float4*)(Op + (((size_t)(b * split + s) * N_ + n) << 6) + f4 * 4);
    O.x += v.x; O.y += v.y; O.z += v.z; O.w += v.w;
  }
  const float inv = 1.f / L;
  bf16x4 o;
  o[0] = f2bf(O.x * inv); o[1] = f2bf(O.y * inv);
  o[2] = f2bf(O.z * inv); o[3] = f2bf(O.w * inv);
  *(bf16x4*)(ob + (size_t)gid4 * 4) = o;
}

// ---------------- final conv as implicit-GEMM MFMA: 32 px/block (control) ----------------
__global__ __launch_bounds__(256) void conv_out_mfma(
    const short* __restrict__ ab, const short* __restrict__ Wt,
    const float* __restrict__ br, float* __restrict__ out)
{
  const int lane = threadIdx.x & 63;
  const int w    = threadIdx.x >> 6;
  const int lrow = lane & 15;
  const int lkb  = lane >> 4;
  const int p0   = blockIdx.x << 5;
  const int b    = p0 >> 12;
  const int y    = (p0 >> 6) & 63;
  const int x0   = p0 & 63;

  f32x4 acc[2];
  #pragma unroll
  for (int m = 0; m < 2; ++m)
    #pragma unroll
    for (int i = 0; i < 4; ++i) acc[m][i] = 0.f;
  const short* wr = Wt + (192 + w * 16 + lrow) * 576;

  #pragma unroll
  for (int ks = 0; ks < 18; ++ks){
    const int kxy = ks >> 1;
    const int ky  = kxy / 3;
    const int kx  = kxy - ky * 3;
    const int ci0 = (ks & 1) << 5;
    const int yy  = y + ky - 1;
    const bf16x8 w8 = *(const bf16x8*)(wr + ks * 32 + lkb * 8);
    #pragma unroll
    for (int m = 0; m < 2; ++m){
      const int xx = x0 + m * 16 + lrow + kx - 1;
      bf16x8 a = {0,0,0,0,0,0,0,0};
      if ((unsigned)yy < 64u && (unsigned)xx < 64u)
        a = *(const bf16x8*)(ab + ((((b << 6) + yy) << 6) + xx) * 64 + ci0 + lkb * 8);
      acc[m] = __builtin_amdgcn_mfma_f32_16x16x32_bf16(a, w8, acc[m], 0, 0, 0);
    }
  }
  const int oc = w * 16 + lrow;
  const float bb = br[oc];
  #pragma unroll
  for (int m = 0; m < 2; ++m)
    #pragma unroll
    for (int i = 0; i < 4; ++i){
      const int p = p0 + m * 16 + (lkb << 2) + i;
      out[(size_t)p * 64 + oc] = fmaxf(acc[m][i] + bb, 0.f);
    }
}

extern "C" void kernel_launch(void* const* d_in, const int* in_sizes, int n_in,
                              void* d_out, int out_size, void* d_ws, size_t ws_size,
                              hipStream_t stream)
{
  const float* x  = (const float*)d_in[0];
  const float* Wk = (const float*)d_in[1];
  const float* bk = (const float*)d_in[2];
  const float* Wq = (const float*)d_in[3];
  const float* bq = (const float*)d_in[4];
  const float* Wv = (const float*)d_in[5];
  const float* bv = (const float*)d_in[6];
  const float* Wr = (const float*)d_in[7];
  const float* br = (const float*)d_in[8];
  float* out = (float*)d_out;

  const size_t BNF = (size_t)B_ * N_ * F_;
  const size_t fixed_shorts = BNF * 5 + 256 * 576;  // xb16, q, k, vt, attnb, Wt
  const size_t fixed_bytes  = fixed_shorts * 2;
  int split = 8;
  while (split > 1 &&
         fixed_bytes + (size_t)split * (BNF * 4 + (size_t)B_ * N_ * 4) > ws_size)
    split >>= 1;

  short* xb16 = (short*)d_ws;
  short* Wt   = xb16 + BNF;
  short* qw   = Wt + 256 * 576;
  short* kw   = qw + BNF;
  short* vt   = kw + BNF;
  short* attnb= vt + BNF;
  float* Op   = (float*)(attnb + BNF);              // fp32 partials
  float* lp   = Op + (size_t)split * BNF;

  hipLaunchKernelGGL(prep_kernel, dim3(1600), dim3(256), 0, stream,
                     x, Wk, Wq, Wv, Wr, xb16, Wt);
  hipLaunchKernelGGL(conv_qkv_mfma, dim3(512), dim3(256), 0, stream,
                     xb16, Wt, bk, bq, bv, qw, kw, vt);
  hipLaunchKernelGGL(attn_kernel, dim3(B_ * 16 * split), dim3(512), 0, stream,
                     qw, kw, vt, Op, lp, split);
  hipLaunchKernelGGL(combine_kernel, dim3((B_ * N_ * F_) / 1024), dim3(256), 0, stream,
                     Op, lp, attnb, split);
  hipLaunchKernelGGL(conv_out_mfma, dim3(512), dim3(256), 0, stream,
                     attnb, Wt, br, out);
}

// Round 23
// 90.981 us; speedup vs baseline: 1.0493x; 1.0493x over previous
//
#include <hip/hip_runtime.h>
#include <hip/hip_bf16.h>
#include <math.h>

#define B_ 4
#define H_ 64
#define W_ 64
#define C_ 64
#define F_ 64
#define N_ 4096

typedef __attribute__((ext_vector_type(8))) short bf16x8;
typedef __attribute__((ext_vector_type(4))) short bf16x4;
typedef __attribute__((ext_vector_type(4))) float f32x4;
typedef __attribute__((ext_vector_type(2))) int i32x2;

#define GLOAD_LDS(g, l) \
  __builtin_amdgcn_global_load_lds( \
      (__attribute__((address_space(1))) const void*)(g), \
      (__attribute__((address_space(3))) void*)(l), 16, 0, 0)

static __device__ __forceinline__ short f2bf(float f){
  union { __hip_bfloat16 h; short s; } u;
  u.h = __float2bfloat16(f);
  return u.s;
}

// ---------------- prep: weights HWIO fp32 -> Wt[256][576] bf16 (x conversion folded into conv) ----
__global__ __launch_bounds__(256) void prep_kernel(
    const float* __restrict__ Wk, const float* __restrict__ Wq,
    const float* __restrict__ Wv, const float* __restrict__ Wr,
    short* __restrict__ Wt)
{
  const int gid = blockIdx.x * 256 + threadIdx.x;    // 256*576
  const int oc = gid / 576;
  const int kk = gid % 576;                          // (ky*3+kx)*64 + ci
  const int srcofs = (kk >> 6) * 4096 + (kk & 63) * 64 + (oc & 63);
  const float* src = (oc < 64) ? Wk : (oc < 128) ? Wq : (oc < 192) ? Wv : Wr;
  Wt[gid] = f2bf(src[srcofs]);
}

// ---------------- conv QKV as implicit-GEMM MFMA: 32 px/block, fp32 x + inline bf16 convert ----------
__global__ __launch_bounds__(256) void conv_qkv_mfma(
    const float* __restrict__ x, const short* __restrict__ Wt,
    const float* __restrict__ bk, const float* __restrict__ bq,
    const float* __restrict__ bv,
    short* __restrict__ qo, short* __restrict__ ko, short* __restrict__ vt)
{
  const int lane = threadIdx.x & 63;
  const int w    = threadIdx.x >> 6;
  const int lrow = lane & 15;
  const int lkb  = lane >> 4;
  const int p0   = blockIdx.x << 5;
  const int b    = p0 >> 12;
  const int y    = (p0 >> 6) & 63;
  const int x0   = p0 & 63;

  f32x4 ak[2], aq[2], av[2];
  #pragma unroll
  for (int m = 0; m < 2; ++m)
    #pragma unroll
    for (int i = 0; i < 4; ++i){ ak[m][i] = 0.f; aq[m][i] = 0.f; av[m][i] = 0.f; }

  const short* wr_k = Wt + (      w * 16 + lrow) * 576;
  const short* wr_q = Wt + ( 64 + w * 16 + lrow) * 576;
  const short* wr_v = Wt + (128 + w * 16 + lrow) * 576;

  #pragma unroll
  for (int ks = 0; ks < 18; ++ks){
    const int kxy = ks >> 1;
    const int ky  = kxy / 3;
    const int kx  = kxy - ky * 3;
    const int ci0 = (ks & 1) << 5;
    const int yy  = y + ky - 1;
    const bf16x8 wk8 = *(const bf16x8*)(wr_k + ks * 32 + lkb * 8);
    const bf16x8 wq8 = *(const bf16x8*)(wr_q + ks * 32 + lkb * 8);
    const bf16x8 wv8 = *(const bf16x8*)(wr_v + ks * 32 + lkb * 8);
    #pragma unroll
    for (int m = 0; m < 2; ++m){
      const int xx = x0 + m * 16 + lrow + kx - 1;
      bf16x8 a = {0,0,0,0,0,0,0,0};
      if ((unsigned)yy < 64u && (unsigned)xx < 64u){
        const float* xp = x + (size_t)((((b << 6) + yy) << 6) + xx) * 64 + ci0 + lkb * 8;
        const float4 v0 = *(const float4*)xp;
        const float4 v1 = *(const float4*)(xp + 4);
        a[0] = f2bf(v0.x); a[1] = f2bf(v0.y); a[2] = f2bf(v0.z); a[3] = f2bf(v0.w);
        a[4] = f2bf(v1.x); a[5] = f2bf(v1.y); a[6] = f2bf(v1.z); a[7] = f2bf(v1.w);
      }
      ak[m] = __builtin_amdgcn_mfma_f32_16x16x32_bf16(a, wk8, ak[m], 0, 0, 0);
      aq[m] = __builtin_amdgcn_mfma_f32_16x16x32_bf16(a, wq8, aq[m], 0, 0, 0);
      av[m] = __builtin_amdgcn_mfma_f32_16x16x32_bf16(a, wv8, av[m], 0, 0, 0);
    }
  }
  const int oc = w * 16 + lrow;
  const float bkv = bk[oc], bqv = bq[oc], bvv = bv[oc];
  #pragma unroll
  for (int m = 0; m < 2; ++m){
    bf16x4 vp;
    #pragma unroll
    for (int i = 0; i < 4; ++i){
      const int p = p0 + m * 16 + (lkb << 2) + i;
      const float kvv = ak[m][i] + bkv;
      ko[p * 64 + oc] = f2bf(kvv > 0.f ? kvv : expm1f(kvv));            // elu
      const float qvv = aq[m][i] + bqv;
      const float qe  = (qvv > 0.f ? qvv : expm1f(qvv)) * 0.125f;       // elu * 1/sqrt(F)
      qo[p * 64 + oc] = f2bf(qe);
      const float vvv = av[m][i] + bvv;
      vp[i] = f2bf(vvv > 0.f ? vvv : 0.f);                              // relu
    }
    *(bf16x4*)(vt + ((size_t)(b * 64 + oc)) * 4096 + (p0 & 4095) + m * 16 + (lkb << 2)) = vp;
  }
}

// ---------------- flash attention (r19-exact): 8 waves/block, swapped QK^T, K+V DMA-staged,
//                  V-frags loaded per-group from LDS (NO register hoist — r22 proved it spills) ----
__global__ __launch_bounds__(512, 4) void attn_kernel(
    const short* __restrict__ q, const short* __restrict__ k,
    const short* __restrict__ vt, float* __restrict__ Op,
    float* __restrict__ lp, int split)
{
  const int tid  = threadIdx.x;
  const int lane = tid & 63;
  const int wv   = tid >> 6;               // 0..7
  const int lrow = lane & 15;
  const int lkb  = lane >> 4;

  const int bid  = blockIdx.x;
  const int b    = bid / (16 * split);
  const int rem  = bid % (16 * split);
  const int rt   = rem / split;            // 256-row tile (0..15)
  const int sp   = rem % split;
  const int rbase = (rt << 8) + (wv << 5); // this wave's 32 rows
  const int tiles = (N_ / 64) / split;
  const int ct0   = sp * tiles;

  const short* qb = q  + (size_t)b * N_ * F_;
  const short* kb = k  + (size_t)b * N_ * F_;
  const short* vb = vt + (size_t)b * F_ * N_;

  // Q fragments (B-operand of the swapped QK^T)
  const bf16x8 aq00 = *(const bf16x8*)(qb + (rbase +      lrow) * F_ + lkb * 8);
  const bf16x8 aq01 = *(const bf16x8*)(qb + (rbase +      lrow) * F_ + 32 + lkb * 8);
  const bf16x8 aq10 = *(const bf16x8*)(qb + (rbase + 16 + lrow) * F_ + lkb * 8);
  const bf16x8 aq11 = *(const bf16x8*)(qb + (rbase + 16 + lrow) * F_ + 32 + lkb * 8);

  __shared__ short kbuf[2][64 * 64];       // 16 KB
  __shared__ short vbuf[2][64 * 64];       // 16 KB
  __shared__ short pbuf[8][16][64];        // 16 KB: per-wave, shared across row groups

  // staging via global_load_lds: LDS dest LINEAR (tid*16); XOR swizzle applied to the
  // GLOBAL source chunk (m201 both-sides rule); read side unchanged.
  const int srow  = tid >> 3;              // 0..63
  const int sc16s = (tid & 7) ^ (srow & 7);  // pre-swizzled source chunk

  f32x4 oacc[2][4];
  float l_r[2] = {0.f, 0.f};
  #pragma unroll
  for (int g = 0; g < 2; ++g)
    #pragma unroll
    for (int fs = 0; fs < 4; ++fs)
      #pragma unroll
      for (int i = 0; i < 4; ++i) oacc[g][fs][i] = 0.f;

  // ---- stage tile 0 (DMA) ----
  int cbase = ct0 << 6;
  GLOAD_LDS(kb + (cbase + srow) * 64 + sc16s * 8, (char*)kbuf[0] + tid * 16);
  GLOAD_LDS(vb + (size_t)srow * N_ + cbase + sc16s * 8, (char*)vbuf[0] + tid * 16);
  __syncthreads();

  int cur = 0;
  for (int t = 0; t < tiles; ++t){
    cbase = (ct0 + t) << 6;
    // issue next-tile DMA into the just-freed buffer (drained at this tile's end barrier)
    if (t + 1 < tiles){
      const int cb2 = (ct0 + t + 1) << 6;
      const int nxt = cur ^ 1;
      GLOAD_LDS(kb + (cb2 + srow) * 64 + sc16s * 8, (char*)kbuf[nxt] + tid * 16);
      GLOAD_LDS(vb + (size_t)srow * N_ + cb2 + sc16s * 8, (char*)vbuf[nxt] + tid * 16);
    }
    const char* kc = (const char*)kbuf[cur];
    const char* vc = (const char*)vbuf[cur];
    // ---- S^T = K Q^T (A = K-frag from LDS, B = Q regs) ----
    f32x4 s0[4], s1[4];
    #pragma unroll
    for (int n = 0; n < 4; ++n){
      #pragma unroll
      for (int i = 0; i < 4; ++i){ s0[n][i] = 0.f; s1[n][i] = 0.f; }
    }
    __builtin_amdgcn_s_setprio(1);
    #pragma unroll
    for (int n = 0; n < 4; ++n){
      const int r   = n * 16 + lrow;
      const int swz = (r & 7) << 4;
      const bf16x8 b0 = *(const bf16x8*)(kc + r * 128 + ((lkb * 16) ^ swz));
      const bf16x8 b1 = *(const bf16x8*)(kc + r * 128 + ((64 + lkb * 16) ^ swz));
      s0[n] = __builtin_amdgcn_mfma_f32_16x16x32_bf16(b0, aq00, s0[n], 0, 0, 0);
      s0[n] = __builtin_amdgcn_mfma_f32_16x16x32_bf16(b1, aq01, s0[n], 0, 0, 0);
      s1[n] = __builtin_amdgcn_mfma_f32_16x16x32_bf16(b0, aq10, s1[n], 0, 0, 0);
      s1[n] = __builtin_amdgcn_mfma_f32_16x16x32_bf16(b1, aq11, s1[n], 0, 0, 0);
    }
    __builtin_amdgcn_s_setprio(0);
    const int rswz = (lrow & 7) << 4;
    char* pgc = (char*)&pbuf[wv][0][0];
    #pragma unroll
    for (int g = 0; g < 2; ++g){
      f32x4* s = g ? s1 : s0;
      // ---- diagonal: only when this wave's 16 q-rows fall inside this tile ----
      const int dq = rbase + g * 16 - cbase;     // wave-uniform
      if (dq >= 0 && dq < 64){
        #pragma unroll
        for (int n = 0; n < 4; ++n)
          if (dq == n * 16){
            const int di = lrow - (lkb << 2);
            #pragma unroll
            for (int i = 0; i < 4; ++i)
              if (di == i) s[n][i] = 0.f;
          }
      }
      // ---- p = exp(s-16); lane-local l; vector P store (k lane-contiguous) ----
      #pragma unroll
      for (int n = 0; n < 4; ++n){
        union { float f; unsigned u; } c0, c1, c2, c3;
        c0.f = __expf(s[n][0] - 16.f);
        c1.f = __expf(s[n][1] - 16.f);
        c2.f = __expf(s[n][2] - 16.f);
        c3.f = __expf(s[n][3] - 16.f);
        l_r[g] += (c0.f + c1.f) + (c2.f + c3.f);
        i32x2 pk;
        pk[0] = (int)((c1.u & 0xFFFF0000u) | (c0.u >> 16));   // bf16 trunc pack
        pk[1] = (int)((c3.u & 0xFFFF0000u) | (c2.u >> 16));
        *(i32x2*)(pgc + lrow * 128 + ((n * 32 + lkb * 8) ^ rswz)) = pk;
      }
      // ---- A-frag P reads + PV (V frags read from LDS per group: cheap, no reg pressure) ----
      const bf16x8 pa0 = *(const bf16x8*)(pgc + lrow * 128 + ((lkb * 16) ^ rswz));
      const bf16x8 pa1 = *(const bf16x8*)(pgc + lrow * 128 + ((64 + lkb * 16) ^ rswz));
      __builtin_amdgcn_s_setprio(1);
      #pragma unroll
      for (int kc2 = 0; kc2 < 2; ++kc2){
        const bf16x8 pa = kc2 ? pa1 : pa0;
        #pragma unroll
        for (int fs = 0; fs < 4; ++fs){
          const int r   = fs * 16 + lrow;
          const int swz = (r & 7) << 4;
          const bf16x8 bvf = *(const bf16x8*)(vc + r * 128 + ((kc2 * 64 + lkb * 16) ^ swz));
          oacc[g][fs] = __builtin_amdgcn_mfma_f32_16x16x32_bf16(pa, bvf, oacc[g][fs], 0, 0, 0);
        }
      }
      __builtin_amdgcn_s_setprio(0);
    }
    // ---- single barrier per tile (drains the next-tile DMA + converges readers) ----
    __syncthreads();
    cur ^= 1;
  }
  // ---- l: single cross-lane reduce (lanes lrow,+16,+32,+48 share q-row) ----
  #pragma unroll
  for (int g = 0; g < 2; ++g){
    l_r[g] += __shfl_xor(l_r[g], 16, 64);
    l_r[g] += __shfl_xor(l_r[g], 32, 64);
  }
  // ---- store fp32 unnormalized partials (coalesced) + l ----
  float* Ob = Op + (size_t)(b * split + sp) * N_ * F_;
  #pragma unroll
  for (int g = 0; g < 2; ++g){
    #pragma unroll
    for (int i = 0; i < 4; ++i){
      const int row = rbase + g * 16 + lkb * 4 + i;
      #pragma unroll
      for (int fs = 0; fs < 4; ++fs)
        Ob[(size_t)row * F_ + fs * 16 + lrow] = oacc[g][fs][i];
    }
    if (lane < 16)
      lp[(size_t)(b * split + sp) * N_ + rbase + g * 16 + lane] = l_r[g];
  }
}

// ---------------- combine fp32 partials, float4-vectorized -> bf16 ----------------
__global__ __launch_bounds__(256) void combine_kernel(
    const float* __restrict__ Op, const float* __restrict__ lp,
    short* __restrict__ ob, int split)
{
  const int gid4 = blockIdx.x * 256 + threadIdx.x;   // over B*N*F/4
  const int f4 = gid4 & 15;
  const int n  = (gid4 >> 4) & (N_ - 1);
  const int b  = gid4 >> 16;
  float L = 0.f;
  float4 O = {0.f, 0.f, 0.f, 0.f};
  for (int s = 0; s < split; ++s){
    L += lp[(size_t)(b * split + s) * N_ + n];
    const float4 v = *(const float4*)(Op + (((size_t)(b * split + s) * N_ + n) << 6) + f4 * 4);
    O.x += v.x; O.y += v.y; O.z += v.z; O.w += v.w;
  }
  const float inv = 1.f / L;
  bf16x4 o;
  o[0] = f2bf(O.x * inv); o[1] = f2bf(O.y * inv);
  o[2] = f2bf(O.z * inv); o[3] = f2bf(O.w * inv);
  *(bf16x4*)(ob + (size_t)gid4 * 4) = o;
}

// ---------------- final conv as implicit-GEMM MFMA: 32 px/block (control) ----------------
__global__ __launch_bounds__(256) void conv_out_mfma(
    const short* __restrict__ ab, const short* __restrict__ Wt,
    const float* __restrict__ br, float* __restrict__ out)
{
  const int lane = threadIdx.x & 63;
  const int w    = threadIdx.x >> 6;
  const int lrow = lane & 15;
  const int lkb  = lane >> 4;
  const int p0   = blockIdx.x << 5;
  const int b    = p0 >> 12;
  const int y    = (p0 >> 6) & 63;
  const int x0   = p0 & 63;

  f32x4 acc[2];
  #pragma unroll
  for (int m = 0; m < 2; ++m)
    #pragma unroll
    for (int i = 0; i < 4; ++i) acc[m][i] = 0.f;
  const short* wr = Wt + (192 + w * 16 + lrow) * 576;

  #pragma unroll
  for (int ks = 0; ks < 18; ++ks){
    const int kxy = ks >> 1;
    const int ky  = kxy / 3;
    const int kx  = kxy - ky * 3;
    const int ci0 = (ks & 1) << 5;
    const int yy  = y + ky - 1;
    const bf16x8 w8 = *(const bf16x8*)(wr + ks * 32 + lkb * 8);
    #pragma unroll
    for (int m = 0; m < 2; ++m){
      const int xx = x0 + m * 16 + lrow + kx - 1;
      bf16x8 a = {0,0,0,0,0,0,0,0};
      if ((unsigned)yy < 64u && (unsigned)xx < 64u)
        a = *(const bf16x8*)(ab + ((((b << 6) + yy) << 6) + xx) * 64 + ci0 + lkb * 8);
      acc[m] = __builtin_amdgcn_mfma_f32_16x16x32_bf16(a, w8, acc[m], 0, 0, 0);
    }
  }
  const int oc = w * 16 + lrow;
  const float bb = br[oc];
  #pragma unroll
  for (int m = 0; m < 2; ++m)
    #pragma unroll
    for (int i = 0; i < 4; ++i){
      const int p = p0 + m * 16 + (lkb << 2) + i;
      out[(size_t)p * 64 + oc] = fmaxf(acc[m][i] + bb, 0.f);
    }
}

extern "C" void kernel_launch(void* const* d_in, const int* in_sizes, int n_in,
                              void* d_out, int out_size, void* d_ws, size_t ws_size,
                              hipStream_t stream)
{
  const float* x  = (const float*)d_in[0];
  const float* Wk = (const float*)d_in[1];
  const float* bk = (const float*)d_in[2];
  const float* Wq = (const float*)d_in[3];
  const float* bq = (const float*)d_in[4];
  const float* Wv = (const float*)d_in[5];
  const float* bv = (const float*)d_in[6];
  const float* Wr = (const float*)d_in[7];
  const float* br = (const float*)d_in[8];
  float* out = (float*)d_out;

  const size_t BNF = (size_t)B_ * N_ * F_;
  // ws: Wt (256*576 bf16) + q + k + vt + attnb (bf16) + Op (fp32) + lp
  const size_t fixed_shorts = BNF * 4 + 256 * 576;
  const size_t fixed_bytes  = fixed_shorts * 2;
  int split = 8;
  while (split > 1 &&
         fixed_bytes + (size_t)split * (BNF * 4 + (size_t)B_ * N_ * 4) > ws_size)
    split >>= 1;

  short* Wt   = (short*)d_ws;
  short* qw   = Wt + 256 * 576;
  short* kw   = qw + BNF;
  short* vt   = kw + BNF;
  short* attnb= vt + BNF;
  float* Op   = (float*)(attnb + BNF);              // fp32 partials
  float* lp   = Op + (size_t)split * BNF;

  hipLaunchKernelGGL(prep_kernel, dim3(576), dim3(256), 0, stream,
                     Wk, Wq, Wv, Wr, Wt);
  hipLaunchKernelGGL(conv_qkv_mfma, dim3(512), dim3(256), 0, stream,
                     x, Wt, bk, bq, bv, qw, kw, vt);
  hipLaunchKernelGGL(attn_kernel, dim3(B_ * 16 * split), dim3(512), 0, stream,
                     qw, kw, vt, Op, lp, split);
  hipLaunchKernelGGL(combine_kernel, dim3((B_ * N_ * F_) / 1024), dim3(256), 0, stream,
                     Op, lp, attnb, split);
  hipLaunchKernelGGL(conv_out_mfma, dim3(512), dim3(256), 0, stream,
                     attnb, Wt, br, out);
}

// Round 24
// 82.700 us; speedup vs baseline: 1.1544x; 1.1001x over previous
//
#include <hip/hip_runtime.h>
#include <hip/hip_bf16.h>
#include <math.h>

#define B_ 4
#define H_ 64
#define W_ 64
#define C_ 64
#define F_ 64
#define N_ 4096

typedef __attribute__((ext_vector_type(8))) short bf16x8;
typedef __attribute__((ext_vector_type(4))) short bf16x4;
typedef __attribute__((ext_vector_type(4))) float f32x4;
typedef __attribute__((ext_vector_type(2))) int i32x2;

#define GLOAD_LDS(g, l) \
  __builtin_amdgcn_global_load_lds( \
      (__attribute__((address_space(1))) const void*)(g), \
      (__attribute__((address_space(3))) void*)(l), 16, 0, 0)

static __device__ __forceinline__ short f2bf(float f){
  union { __hip_bfloat16 h; short s; } u;
  u.h = __float2bfloat16(f);
  return u.s;
}

// ---------------- merged prep: x fp32->bf16 (blocks 0..1023) + weights->Wt (blocks 1024..1599) ----
__global__ __launch_bounds__(256) void prep_kernel(
    const float* __restrict__ x,
    const float* __restrict__ Wk, const float* __restrict__ Wq,
    const float* __restrict__ Wv, const float* __restrict__ Wr,
    short* __restrict__ xb, short* __restrict__ Wt)
{
  const int bid = blockIdx.x;
  if (bid < 1024){
    const int i4 = bid * 256 + threadIdx.x;          // over B*N*C/4
    const float4 v = ((const float4*)x)[i4];
    bf16x4 o;
    o[0] = f2bf(v.x); o[1] = f2bf(v.y); o[2] = f2bf(v.z); o[3] = f2bf(v.w);
    ((bf16x4*)xb)[i4] = o;
  } else {
    const int gid = (bid - 1024) * 256 + threadIdx.x;  // 256*576
    const int oc = gid / 576;
    const int kk = gid % 576;                          // (ky*3+kx)*64 + ci
    const int srcofs = (kk >> 6) * 4096 + (kk & 63) * 64 + (oc & 63);
    const float* src = (oc < 64) ? Wk : (oc < 128) ? Wq : (oc < 192) ? Wv : Wr;
    Wt[gid] = f2bf(src[srcofs]);
  }
}

// ---------------- conv QKV as implicit-GEMM MFMA: 64 px/block (full row), 4 M-subtiles ----------------
__global__ __launch_bounds__(256) void conv_qkv_mfma(
    const short* __restrict__ xb, const short* __restrict__ Wt,
    const float* __restrict__ bk, const float* __restrict__ bq,
    const float* __restrict__ bv,
    short* __restrict__ qo, short* __restrict__ ko, short* __restrict__ vt)
{
  const int lane = threadIdx.x & 63;
  const int w    = threadIdx.x >> 6;
  const int lrow = lane & 15;
  const int lkb  = lane >> 4;
  const int p0   = blockIdx.x << 6;      // one full image row
  const int b    = p0 >> 12;
  const int y    = (p0 >> 6) & 63;

  f32x4 ak[4], aq[4], av[4];
  #pragma unroll
  for (int m = 0; m < 4; ++m)
    #pragma unroll
    for (int i = 0; i < 4; ++i){ ak[m][i] = 0.f; aq[m][i] = 0.f; av[m][i] = 0.f; }

  const short* wr_k = Wt + (      w * 16 + lrow) * 576;
  const short* wr_q = Wt + ( 64 + w * 16 + lrow) * 576;
  const short* wr_v = Wt + (128 + w * 16 + lrow) * 576;

  #pragma unroll
  for (int ks = 0; ks < 18; ++ks){
    const int kxy = ks >> 1;
    const int ky  = kxy / 3;
    const int kx  = kxy - ky * 3;
    const int ci0 = (ks & 1) << 5;
    const int yy  = y + ky - 1;
    const bf16x8 wk8 = *(const bf16x8*)(wr_k + ks * 32 + lkb * 8);
    const bf16x8 wq8 = *(const bf16x8*)(wr_q + ks * 32 + lkb * 8);
    const bf16x8 wv8 = *(const bf16x8*)(wr_v + ks * 32 + lkb * 8);
    #pragma unroll
    for (int m = 0; m < 4; ++m){
      const int xx = m * 16 + lrow + kx - 1;
      bf16x8 a = {0,0,0,0,0,0,0,0};
      if ((unsigned)yy < 64u && (unsigned)xx < 64u)
        a = *(const bf16x8*)(xb + ((((b << 6) + yy) << 6) + xx) * 64 + ci0 + lkb * 8);
      ak[m] = __builtin_amdgcn_mfma_f32_16x16x32_bf16(a, wk8, ak[m], 0, 0, 0);
      aq[m] = __builtin_amdgcn_mfma_f32_16x16x32_bf16(a, wq8, aq[m], 0, 0, 0);
      av[m] = __builtin_amdgcn_mfma_f32_16x16x32_bf16(a, wv8, av[m], 0, 0, 0);
    }
  }
  const int oc = w * 16 + lrow;
  const float bkv = bk[oc], bqv = bq[oc], bvv = bv[oc];
  #pragma unroll
  for (int m = 0; m < 4; ++m){
    bf16x4 vp;
    #pragma unroll
    for (int i = 0; i < 4; ++i){
      const int p = p0 + m * 16 + (lkb << 2) + i;
      const float kvv = ak[m][i] + bkv;
      ko[p * 64 + oc] = f2bf(kvv > 0.f ? kvv : expm1f(kvv));            // elu
      const float qvv = aq[m][i] + bqv;
      const float qe  = (qvv > 0.f ? qvv : expm1f(qvv)) * 0.125f;       // elu * 1/sqrt(F)
      qo[p * 64 + oc] = f2bf(qe);
      const float vvv = av[m][i] + bvv;
      vp[i] = f2bf(vvv > 0.f ? vvv : 0.f);                              // relu
    }
    *(bf16x4*)(vt + ((size_t)(b * 64 + oc)) * 4096 + (p0 & 4095) + m * 16 + (lkb << 2)) = vp;
  }
}

// ---------------- flash attention (r17-exact): 8 waves/block, swapped QK^T, shared 16KB pbuf,
//                  K+V staged via global_load_lds (linear LDS dest, pre-swizzled source) ----------------
__global__ __launch_bounds__(512, 4) void attn_kernel(
    const short* __restrict__ q, const short* __restrict__ k,
    const short* __restrict__ vt, float* __restrict__ Op,
    float* __restrict__ lp, int split)
{
  const int tid  = threadIdx.x;
  const int lane = tid & 63;
  const int wv   = tid >> 6;               // 0..7
  const int lrow = lane & 15;
  const int lkb  = lane >> 4;

  const int bid  = blockIdx.x;
  const int b    = bid / (16 * split);
  const int rem  = bid % (16 * split);
  const int rt   = rem / split;            // 256-row tile (0..15)
  const int sp   = rem % split;
  const int rbase = (rt << 8) + (wv << 5); // this wave's 32 rows
  const int tiles = (N_ / 64) / split;
  const int ct0   = sp * tiles;

  const short* qb = q  + (size_t)b * N_ * F_;
  const short* kb = k  + (size_t)b * N_ * F_;
  const short* vb = vt + (size_t)b * F_ * N_;

  // Q fragments (B-operand of the swapped QK^T)
  const bf16x8 aq00 = *(const bf16x8*)(qb + (rbase +      lrow) * F_ + lkb * 8);
  const bf16x8 aq01 = *(const bf16x8*)(qb + (rbase +      lrow) * F_ + 32 + lkb * 8);
  const bf16x8 aq10 = *(const bf16x8*)(qb + (rbase + 16 + lrow) * F_ + lkb * 8);
  const bf16x8 aq11 = *(const bf16x8*)(qb + (rbase + 16 + lrow) * F_ + 32 + lkb * 8);

  __shared__ short kbuf[2][64 * 64];       // 16 KB
  __shared__ short vbuf[2][64 * 64];       // 16 KB
  __shared__ short pbuf[8][16][64];        // 16 KB: per-wave, shared across row groups

  // staging via global_load_lds: LDS dest LINEAR (tid*16); XOR swizzle applied to the
  // GLOBAL source chunk (m201 both-sides rule); read side unchanged.
  const int srow  = tid >> 3;              // 0..63
  const int sc16s = (tid & 7) ^ (srow & 7);  // pre-swizzled source chunk

  f32x4 oacc[2][4];
  float l_r[2] = {0.f, 0.f};
  #pragma unroll
  for (int g = 0; g < 2; ++g)
    #pragma unroll
    for (int fs = 0; fs < 4; ++fs)
      #pragma unroll
      for (int i = 0; i < 4; ++i) oacc[g][fs][i] = 0.f;

  // ---- stage tile 0 (DMA) ----
  int cbase = ct0 << 6;
  GLOAD_LDS(kb + (cbase + srow) * 64 + sc16s * 8, (char*)kbuf[0] + tid * 16);
  GLOAD_LDS(vb + (size_t)srow * N_ + cbase + sc16s * 8, (char*)vbuf[0] + tid * 16);
  __syncthreads();

  int cur = 0;
  for (int t = 0; t < tiles; ++t){
    cbase = (ct0 + t) << 6;
    // issue next-tile DMA into the just-freed buffer (drained at this tile's end barrier)
    if (t + 1 < tiles){
      const int cb2 = (ct0 + t + 1) << 6;
      const int nxt = cur ^ 1;
      GLOAD_LDS(kb + (cb2 + srow) * 64 + sc16s * 8, (char*)kbuf[nxt] + tid * 16);
      GLOAD_LDS(vb + (size_t)srow * N_ + cb2 + sc16s * 8, (char*)vbuf[nxt] + tid * 16);
    }
    const char* kc = (const char*)kbuf[cur];
    const char* vc = (const char*)vbuf[cur];
    // ---- S^T = K Q^T (A = K-frag from LDS, B = Q regs) ----
    f32x4 s0[4], s1[4];
    #pragma unroll
    for (int n = 0; n < 4; ++n){
      #pragma unroll
      for (int i = 0; i < 4; ++i){ s0[n][i] = 0.f; s1[n][i] = 0.f; }
    }
    __builtin_amdgcn_s_setprio(1);
    #pragma unroll
    for (int n = 0; n < 4; ++n){
      const int r   = n * 16 + lrow;
      const int swz = (r & 7) << 4;
      const bf16x8 b0 = *(const bf16x8*)(kc + r * 128 + ((lkb * 16) ^ swz));
      const bf16x8 b1 = *(const bf16x8*)(kc + r * 128 + ((64 + lkb * 16) ^ swz));
      s0[n] = __builtin_amdgcn_mfma_f32_16x16x32_bf16(b0, aq00, s0[n], 0, 0, 0);
      s0[n] = __builtin_amdgcn_mfma_f32_16x16x32_bf16(b1, aq01, s0[n], 0, 0, 0);
      s1[n] = __builtin_amdgcn_mfma_f32_16x16x32_bf16(b0, aq10, s1[n], 0, 0, 0);
      s1[n] = __builtin_amdgcn_mfma_f32_16x16x32_bf16(b1, aq11, s1[n], 0, 0, 0);
    }
    __builtin_amdgcn_s_setprio(0);
    const int rswz = (lrow & 7) << 4;
    char* pgc = (char*)&pbuf[wv][0][0];
    #pragma unroll
    for (int g = 0; g < 2; ++g){
      f32x4* s = g ? s1 : s0;
      // ---- diagonal: only when this wave's 16 q-rows fall inside this tile ----
      const int dq = rbase + g * 16 - cbase;     // wave-uniform
      if (dq >= 0 && dq < 64){
        #pragma unroll
        for (int n = 0; n < 4; ++n)
          if (dq == n * 16){
            const int di = lrow - (lkb << 2);
            #pragma unroll
            for (int i = 0; i < 4; ++i)
              if (di == i) s[n][i] = 0.f;
          }
      }
      // ---- p = exp(s-16); lane-local l; vector P store (k lane-contiguous) ----
      #pragma unroll
      for (int n = 0; n < 4; ++n){
        union { float f; unsigned u; } c0, c1, c2, c3;
        c0.f = __expf(s[n][0] - 16.f);
        c1.f = __expf(s[n][1] - 16.f);
        c2.f = __expf(s[n][2] - 16.f);
        c3.f = __expf(s[n][3] - 16.f);
        l_r[g] += (c0.f + c1.f) + (c2.f + c3.f);
        i32x2 pk;
        pk[0] = (int)((c1.u & 0xFFFF0000u) | (c0.u >> 16));   // bf16 trunc pack
        pk[1] = (int)((c3.u & 0xFFFF0000u) | (c2.u >> 16));
        *(i32x2*)(pgc + lrow * 128 + ((n * 32 + lkb * 8) ^ rswz)) = pk;
      }
      // ---- A-frag P reads + PV ----
      const bf16x8 pa0 = *(const bf16x8*)(pgc + lrow * 128 + ((lkb * 16) ^ rswz));
      const bf16x8 pa1 = *(const bf16x8*)(pgc + lrow * 128 + ((64 + lkb * 16) ^ rswz));
      __builtin_amdgcn_s_setprio(1);
      #pragma unroll
      for (int kc2 = 0; kc2 < 2; ++kc2){
        const bf16x8 pa = kc2 ? pa1 : pa0;
        #pragma unroll
        for (int fs = 0; fs < 4; ++fs){
          const int r   = fs * 16 + lrow;
          const int swz = (r & 7) << 4;
          const bf16x8 bvf = *(const bf16x8*)(vc + r * 128 + ((kc2 * 64 + lkb * 16) ^ swz));
          oacc[g][fs] = __builtin_amdgcn_mfma_f32_16x16x32_bf16(pa, bvf, oacc[g][fs], 0, 0, 0);
        }
      }
      __builtin_amdgcn_s_setprio(0);
    }
    // ---- single barrier per tile (drains the next-tile DMA + converges readers) ----
    __syncthreads();
    cur ^= 1;
  }
  // ---- l: single cross-lane reduce (lanes lrow,+16,+32,+48 share q-row) ----
  #pragma unroll
  for (int g = 0; g < 2; ++g){
    l_r[g] += __shfl_xor(l_r[g], 16, 64);
    l_r[g] += __shfl_xor(l_r[g], 32, 64);
  }
  // ---- store fp32 unnormalized partials (coalesced) + l ----
  float* Ob = Op + (size_t)(b * split + sp) * N_ * F_;
  #pragma unroll
  for (int g = 0; g < 2; ++g){
    #pragma unroll
    for (int i = 0; i < 4; ++i){
      const int row = rbase + g * 16 + lkb * 4 + i;
      #pragma unroll
      for (int fs = 0; fs < 4; ++fs)
        Ob[(size_t)row * F_ + fs * 16 + lrow] = oacc[g][fs][i];
    }
    if (lane < 16)
      lp[(size_t)(b * split + sp) * N_ + rbase + g * 16 + lane] = l_r[g];
  }
}

// ---------------- combine fp32 partials, float4-vectorized -> bf16 ----------------
__global__ __launch_bounds__(256) void combine_kernel(
    const float* __restrict__ Op, const float* __restrict__ lp,
    short* __restrict__ ob, int split)
{
  const int gid4 = blockIdx.x * 256 + threadIdx.x;   // over B*N*F/4
  const int f4 = gid4 & 15;
  const int n  = (gid4 >> 4) & (N_ - 1);
  const int b  = gid4 >> 16;
  float L = 0.f;
  float4 O = {0.f, 0.f, 0.f, 0.f};
  for (int s = 0; s < split; ++s){
    L += lp[(size_t)(b * split + s) * N_ + n];
    const float4 v = *(const float4*)(Op + (((size_t)(b * split + s) * N_ + n) << 6) + f4 * 4);
    O.x += v.x; O.y += v.y; O.z += v.z; O.w += v.w;
  }
  const float inv = 1.f / L;
  bf16x4 o;
  o[0] = f2bf(O.x * inv); o[1] = f2bf(O.y * inv);
  o[2] = f2bf(O.z * inv); o[3] = f2bf(O.w * inv);
  *(bf16x4*)(ob + (size_t)gid4 * 4) = o;
}

// ---------------- final conv as implicit-GEMM MFMA: 64 px/block (full row), 4 M-subtiles ----------------
__global__ __launch_bounds__(256) void conv_out_mfma(
    const short* __restrict__ ab, const short* __restrict__ Wt,
    const float* __restrict__ br, float* __restrict__ out)
{
  const int lane = threadIdx.x & 63;
  const int w    = threadIdx.x >> 6;
  const int lrow = lane & 15;
  const int lkb  = lane >> 4;
  const int p0   = blockIdx.x << 6;
  const int b    = p0 >> 12;
  const int y    = (p0 >> 6) & 63;

  f32x4 acc[4];
  #pragma unroll
  for (int m = 0; m < 4; ++m)
    #pragma unroll
    for (int i = 0; i < 4; ++i) acc[m][i] = 0.f;
  const short* wr = Wt + (192 + w * 16 + lrow) * 576;

  #pragma unroll
  for (int ks = 0; ks < 18; ++ks){
    const int kxy = ks >> 1;
    const int ky  = kxy / 3;
    const int kx  = kxy - ky * 3;
    const int ci0 = (ks & 1) << 5;
    const int yy  = y + ky - 1;
    const bf16x8 w8 = *(const bf16x8*)(wr + ks * 32 + lkb * 8);
    #pragma unroll
    for (int m = 0; m < 4; ++m){
      const int xx = m * 16 + lrow + kx - 1;
      bf16x8 a = {0,0,0,0,0,0,0,0};
      if ((unsigned)yy < 64u && (unsigned)xx < 64u)
        a = *(const bf16x8*)(ab + ((((b << 6) + yy) << 6) + xx) * 64 + ci0 + lkb * 8);
      acc[m] = __builtin_amdgcn_mfma_f32_16x16x32_bf16(a, w8, acc[m], 0, 0, 0);
    }
  }
  const int oc = w * 16 + lrow;
  const float bb = br[oc];
  #pragma unroll
  for (int m = 0; m < 4; ++m)
    #pragma unroll
    for (int i = 0; i < 4; ++i){
      const int p = p0 + m * 16 + (lkb << 2) + i;
      out[(size_t)p * 64 + oc] = fmaxf(acc[m][i] + bb, 0.f);
    }
}

extern "C" void kernel_launch(void* const* d_in, const int* in_sizes, int n_in,
                              void* d_out, int out_size, void* d_ws, size_t ws_size,
                              hipStream_t stream)
{
  const float* x  = (const float*)d_in[0];
  const float* Wk = (const float*)d_in[1];
  const float* bk = (const float*)d_in[2];
  const float* Wq = (const float*)d_in[3];
  const float* bq = (const float*)d_in[4];
  const float* Wv = (const float*)d_in[5];
  const float* bv = (const float*)d_in[6];
  const float* Wr = (const float*)d_in[7];
  const float* br = (const float*)d_in[8];
  float* out = (float*)d_out;

  const size_t BNF = (size_t)B_ * N_ * F_;
  const size_t fixed_shorts = BNF * 5 + 256 * 576;  // xb16, q, k, vt, attnb, Wt
  const size_t fixed_bytes  = fixed_shorts * 2;
  int split = 8;
  while (split > 1 &&
         fixed_bytes + (size_t)split * (BNF * 4 + (size_t)B_ * N_ * 4) > ws_size)
    split >>= 1;

  short* xb16 = (short*)d_ws;
  short* Wt   = xb16 + BNF;
  short* qw   = Wt + 256 * 576;
  short* kw   = qw + BNF;
  short* vt   = kw + BNF;
  short* attnb= vt + BNF;
  float* Op   = (float*)(attnb + BNF);              // fp32 partials
  float* lp   = Op + (size_t)split * BNF;

  hipLaunchKernelGGL(prep_kernel, dim3(1600), dim3(256), 0, stream,
                     x, Wk, Wq, Wv, Wr, xb16, Wt);
  hipLaunchKernelGGL(conv_qkv_mfma, dim3(256), dim3(256), 0, stream,
                     xb16, Wt, bk, bq, bv, qw, kw, vt);
  hipLaunchKernelGGL(attn_kernel, dim3(B_ * 16 * split), dim3(512), 0, stream,
                     qw, kw, vt, Op, lp, split);
  hipLaunchKernelGGL(combine_kernel, dim3((B_ * N_ * F_) / 1024), dim3(256), 0, stream,
                     Op, lp, attnb, split);
  hipLaunchKernelGGL(conv_out_mfma, dim3(256), dim3(256), 0, stream,
                     attnb, Wt, br, out);
}